// Round 1
// baseline (441.192 us; speedup 1.0000x reference)
//
#include <hip/hip_runtime.h>

// CrossAttentionModel on MI355X (gfx950).
//
// Math: out = softmax((x Wq + bq)(y Wk + bk)^T) (y Wv + bv) Wo + bo
// Restructured (softmax invariant to per-row constants; sum(weights)=1):
//   M = Wq Wk^T [E,F]; wvec = Wk bq [F]; q' = x M + wvec  [B,LQ,F]
//   scores = q' y^T  (contraction F=256)
//   N = Wv Wo [F,E]; cvec = bv Wo + bo
//   out = (softmax(scores) y) N + cvec
// Score path computed with split-bf16 (hi+lo, 3-pass MFMA) for ~f32 accuracy;
// value path in plain bf16.
//
// Workspace use: ~73 MB.

#define DEV static __device__ __forceinline__

typedef __attribute__((ext_vector_type(8))) short s8v;     // 8 bf16 (4 VGPR) MFMA frag
typedef __attribute__((ext_vector_type(4))) float f4v;     // MFMA acc
typedef __attribute__((ext_vector_type(4))) float float4v;
typedef __attribute__((ext_vector_type(4))) unsigned short us4;
typedef __attribute__((ext_vector_type(4))) unsigned int u32x4;
typedef unsigned short u16;
typedef unsigned int u32;

constexpr int BB = 16;
constexpr int LQ = 1024;
constexpr int LK = 2048;
constexpr int E = 512;
constexpr int F = 256;
constexpr int AD = 512;

DEV u16 f2bf(float x) {
    u32 u = __builtin_bit_cast(u32, x);
    u += 0x7fff + ((u >> 16) & 1);
    return (u16)(u >> 16);
}
DEV float bf2f(u16 h) { return __builtin_bit_cast(float, (u32)h << 16); }

DEV f4v MF(s8v a, s8v b, f4v c) {
    return __builtin_amdgcn_mfma_f32_16x16x32_bf16(a, b, c, 0, 0, 0);
}

// ---------------------------------------------------------------------------
// wvec[f] = sum_a Wk[f][a] bq[a] ; cvec[e] = bo[e] + sum_a bv[a] Wo[a][e]
__global__ __launch_bounds__(512) void kvec_kernel(
    const float* __restrict__ Wk, const float* __restrict__ bq,
    const float* __restrict__ bv, const float* __restrict__ Wo,
    const float* __restrict__ bo, float* __restrict__ wvec,
    float* __restrict__ cvec)
{
    int t = threadIdx.x;
    if (t < F) {
        float s = 0.f;
        for (int a = 0; a < AD; ++a) s += Wk[(size_t)t * AD + a] * bq[a];
        wvec[t] = s;
    }
    float s = bo[t];
    for (int a = 0; a < AD; ++a) s += bv[a] * Wo[(size_t)a * E + t];
    cvec[t] = s;
}

// ---------------------------------------------------------------------------
// Split-bf16 NT GEMM: C[m][n] = sum_k A[m][k]*B[n][k], K=512, ld(A)=ld(B)=512.
// Tile 64(M) x 256(N), BK=32, 4 waves (each 32x128).
// MODE 0: A,B f32 -> C f32 (ldc=512)                   [Mt]
// MODE 1: A,B f32 -> split bf16 (Oh,Ol), += wvec (ldc=256)  [q']
// MODE 2: A read transposed A[k][m]; -> bf16 Oh (ldc=256)    [Nt]
template <int MODE>
__global__ __launch_bounds__(256) void splitnt(
    const float* __restrict__ Ag, const float* __restrict__ Bg,
    float* __restrict__ Cf, const float* __restrict__ wv,
    u16* __restrict__ Oh, u16* __restrict__ Ol)
{
    constexpr int LDC = (MODE == 0) ? 512 : 256;
    __shared__ u16 Ash[64][40], Asl[64][40];
    __shared__ u16 Bsh[256][40], Bsl[256][40];

    const int tid = threadIdx.x;
    const int w = tid >> 6, lane = tid & 63;
    const int g = lane >> 4, qn = lane & 15;
    const int wr = w >> 1, wc = w & 1;
    const int m0 = blockIdx.x * 64, n0 = blockIdx.y * 256;

    f4v acc[2][8];
#pragma unroll
    for (int i = 0; i < 2; ++i)
#pragma unroll
        for (int j = 0; j < 8; ++j) acc[i][j] = (f4v){0.f, 0.f, 0.f, 0.f};

    for (int k0 = 0; k0 < 512; k0 += 32) {
        __syncthreads();
        if (MODE != 2) {
            int r = tid & 63, c = (tid >> 6) * 8;
            const float* s = Ag + (size_t)(m0 + r) * 512 + k0 + c;
            float4v v0 = *(const float4v*)s, v1 = *(const float4v*)(s + 4);
            short hh[8], ll[8];
#pragma unroll
            for (int i = 0; i < 8; ++i) {
                float x = (i < 4) ? v0[i] : v1[i - 4];
                u16 h = f2bf(x);
                hh[i] = (short)h;
                ll[i] = (short)f2bf(x - bf2f(h));
            }
            *(s8v*)&Ash[r][c] = (s8v){hh[0],hh[1],hh[2],hh[3],hh[4],hh[5],hh[6],hh[7]};
            *(s8v*)&Asl[r][c] = (s8v){ll[0],ll[1],ll[2],ll[3],ll[4],ll[5],ll[6],ll[7]};
        } else {
            int k = tid >> 3, mc = (tid & 7) * 8;
            const float* s = Ag + (size_t)(k0 + k) * 512 + m0 + mc;
            float4v v0 = *(const float4v*)s, v1 = *(const float4v*)(s + 4);
#pragma unroll
            for (int i = 0; i < 8; ++i) {
                float x = (i < 4) ? v0[i] : v1[i - 4];
                u16 h = f2bf(x);
                Ash[mc + i][k] = h;
                Asl[mc + i][k] = f2bf(x - bf2f(h));
            }
        }
        {
            const float* s = Bg + (size_t)(n0 + tid) * 512 + k0;
#pragma unroll
            for (int c = 0; c < 32; c += 8) {
                float4v v0 = *(const float4v*)(s + c), v1 = *(const float4v*)(s + c + 4);
                short hh[8], ll[8];
#pragma unroll
                for (int i = 0; i < 8; ++i) {
                    float x = (i < 4) ? v0[i] : v1[i - 4];
                    u16 h = f2bf(x);
                    hh[i] = (short)h;
                    ll[i] = (short)f2bf(x - bf2f(h));
                }
                *(s8v*)&Bsh[tid][c] = (s8v){hh[0],hh[1],hh[2],hh[3],hh[4],hh[5],hh[6],hh[7]};
                *(s8v*)&Bsl[tid][c] = (s8v){ll[0],ll[1],ll[2],ll[3],ll[4],ll[5],ll[6],ll[7]};
            }
        }
        __syncthreads();

        s8v ah[2], al[2], bh[8], bl[8];
#pragma unroll
        for (int mt = 0; mt < 2; ++mt) {
            ah[mt] = *(const s8v*)&Ash[wr * 32 + mt * 16 + qn][g * 8];
            al[mt] = *(const s8v*)&Asl[wr * 32 + mt * 16 + qn][g * 8];
        }
#pragma unroll
        for (int nt = 0; nt < 8; ++nt) {
            bh[nt] = *(const s8v*)&Bsh[wc * 128 + nt * 16 + qn][g * 8];
            bl[nt] = *(const s8v*)&Bsl[wc * 128 + nt * 16 + qn][g * 8];
        }
#pragma unroll
        for (int mt = 0; mt < 2; ++mt)
#pragma unroll
            for (int nt = 0; nt < 8; ++nt) {
                acc[mt][nt] = MF(ah[mt], bh[nt], acc[mt][nt]);
                acc[mt][nt] = MF(ah[mt], bl[nt], acc[mt][nt]);
                acc[mt][nt] = MF(al[mt], bh[nt], acc[mt][nt]);
            }
    }

#pragma unroll
    for (int mt = 0; mt < 2; ++mt)
#pragma unroll
        for (int nt = 0; nt < 8; ++nt)
#pragma unroll
            for (int r = 0; r < 4; ++r) {
                int gm = m0 + wr * 32 + mt * 16 + 4 * g + r;
                int gn = n0 + wc * 128 + nt * 16 + qn;
                float v = acc[mt][nt][r];
                if (MODE == 0) {
                    Cf[(size_t)gm * LDC + gn] = v;
                } else if (MODE == 1) {
                    v += wv[gn];
                    u16 h = f2bf(v);
                    Oh[(size_t)gm * LDC + gn] = h;
                    Ol[(size_t)gm * LDC + gn] = f2bf(v - bf2f(h));
                } else {
                    Oh[(size_t)gm * LDC + gn] = f2bf(v);
                }
            }
}

// ---------------------------------------------------------------------------
// prep: split y -> yh/yl bf16 [B][LK][F], and yT bf16 [B][F][LK] (transposed hi)
__global__ __launch_bounds__(256) void prep_kernel(
    const float* __restrict__ y, u16* __restrict__ yh_g,
    u16* __restrict__ yl_g, u16* __restrict__ yT_g)
{
    const int t = threadIdx.x;            // f index 0..255
    const int j0 = blockIdx.x * 64;
    const int b = blockIdx.y;
    u32 pk[32];
#pragma unroll
    for (int jj = 0; jj < 64; ++jj) {
        size_t idx = (size_t)(b * LK + j0 + jj) * F + t;
        float v = y[idx];
        u16 h = f2bf(v);
        u16 lo = f2bf(v - bf2f(h));
        yh_g[idx] = h;
        yl_g[idx] = lo;
        if (jj & 1) pk[jj >> 1] |= (u32)h << 16; else pk[jj >> 1] = (u32)h;
    }
    u32* dst = (u32*)(yT_g + (size_t)(b * F + t) * LK + j0);
#pragma unroll
    for (int i = 0; i < 8; ++i)
        *(u32x4*)(dst + 4 * i) = (u32x4){pk[4*i], pk[4*i+1], pk[4*i+2], pk[4*i+3]};
}

// ---------------------------------------------------------------------------
// Flash attention: per block (q-tile of 64, batch b). 4 waves x 16 q-rows.
// Swapped QK: S'[k][q] = mfma(A=y_tile, B=q'), so each lane owns one q-row's
// scores for 8 of 32 k -> 2-shuffle row reduce. Split-bf16 scores (3-pass).
// ctx[q][f] += P[q][k] * y[k][f] via pLDS round-trip + yT tile.
__global__ __launch_bounds__(256) void flash_kernel(
    const u16* __restrict__ qh_g, const u16* __restrict__ ql_g,
    const u16* __restrict__ yh_g, const u16* __restrict__ yl_g,
    const u16* __restrict__ yT_g, u16* __restrict__ ctx_g)
{
    __shared__ u16 yhA[32][264], ylA[32][264];
    __shared__ u16 yTs[256][40];
    __shared__ u16 pls[4][16][40];

    const int tid = threadIdx.x;
    const int w = tid >> 6, lane = tid & 63;
    const int g = lane >> 4, qn = lane & 15;
    const int b = blockIdx.y;
    const int q0 = blockIdx.x * 64;
    const int qrow = q0 + w * 16 + qn;

    s8v qfh[8], qfl[8];
    {
        const u16* ph = qh_g + (size_t)(b * LQ + qrow) * F;
        const u16* pl = ql_g + (size_t)(b * LQ + qrow) * F;
#pragma unroll
        for (int s = 0; s < 8; ++s) {
            qfh[s] = *(const s8v*)(ph + s * 32 + g * 8);
            qfl[s] = *(const s8v*)(pl + s * 32 + g * 8);
        }
    }
    f4v ctx[16];
#pragma unroll
    for (int n = 0; n < 16; ++n) ctx[n] = (f4v){0.f, 0.f, 0.f, 0.f};
    float m = -3.0e38f, l = 0.f;

    for (int j0 = 0; j0 < LK; j0 += 32) {
        __syncthreads();
        {
            int r = tid >> 3, c = (tid & 7) * 32;
            const u16* sh = yh_g + (size_t)(b * LK + j0 + r) * F + c;
            const u16* sl = yl_g + (size_t)(b * LK + j0 + r) * F + c;
#pragma unroll
            for (int i = 0; i < 4; ++i) {
                *(s8v*)&yhA[r][c + i * 8] = *(const s8v*)(sh + i * 8);
                *(s8v*)&ylA[r][c + i * 8] = *(const s8v*)(sl + i * 8);
            }
            const u16* st = yT_g + (size_t)(b * F + tid) * LK + j0;
#pragma unroll
            for (int i = 0; i < 4; ++i)
                *(s8v*)&yTs[tid][i * 8] = *(const s8v*)(st + i * 8);
        }
        __syncthreads();

        f4v s0 = (f4v){0.f, 0.f, 0.f, 0.f}, s1 = (f4v){0.f, 0.f, 0.f, 0.f};
#pragma unroll
        for (int s = 0; s < 8; ++s) {
            s8v a0h = *(const s8v*)&yhA[qn][s * 32 + g * 8];
            s8v a0l = *(const s8v*)&ylA[qn][s * 32 + g * 8];
            s8v a1h = *(const s8v*)&yhA[16 + qn][s * 32 + g * 8];
            s8v a1l = *(const s8v*)&ylA[16 + qn][s * 32 + g * 8];
            s0 = MF(a0h, qfh[s], s0);
            s0 = MF(a0h, qfl[s], s0);
            s0 = MF(a0l, qfh[s], s0);
            s1 = MF(a1h, qfh[s], s1);
            s1 = MF(a1h, qfl[s], s1);
            s1 = MF(a1l, qfh[s], s1);
        }

        float vmax = fmaxf(fmaxf(fmaxf(s0[0], s0[1]), fmaxf(s0[2], s0[3])),
                           fmaxf(fmaxf(s1[0], s1[1]), fmaxf(s1[2], s1[3])));
        vmax = fmaxf(vmax, __shfl_xor(vmax, 16));
        vmax = fmaxf(vmax, __shfl_xor(vmax, 32));
        float mnew = fmaxf(m, vmax);
        float alpha = __expf(m - mnew);
        float p0[4], p1[4], ps = 0.f;
#pragma unroll
        for (int r = 0; r < 4; ++r) {
            p0[r] = __expf(s0[r] - mnew);
            p1[r] = __expf(s1[r] - mnew);
            ps += p0[r] + p1[r];
        }
        ps += __shfl_xor(ps, 16);
        ps += __shfl_xor(ps, 32);
        l = l * alpha + ps;
        m = mnew;

        *(us4*)&pls[w][qn][4 * g] =
            (us4){f2bf(p0[0]), f2bf(p0[1]), f2bf(p0[2]), f2bf(p0[3])};
        *(us4*)&pls[w][qn][16 + 4 * g] =
            (us4){f2bf(p1[0]), f2bf(p1[1]), f2bf(p1[2]), f2bf(p1[3])};

        float a0 = __shfl(alpha, 4 * g + 0);
        float a1 = __shfl(alpha, 4 * g + 1);
        float a2 = __shfl(alpha, 4 * g + 2);
        float a3 = __shfl(alpha, 4 * g + 3);
        f4v av = (f4v){a0, a1, a2, a3};
#pragma unroll
        for (int n = 0; n < 16; ++n) ctx[n] *= av;

        s8v pf = *(const s8v*)&pls[w][qn][g * 8];
#pragma unroll
        for (int n = 0; n < 16; ++n) {
            s8v bf = *(const s8v*)&yTs[n * 16 + qn][g * 8];
            ctx[n] = MF(pf, bf, ctx[n]);
        }
    }

    float i0 = 1.f / __shfl(l, 4 * g + 0);
    float i1 = 1.f / __shfl(l, 4 * g + 1);
    float i2 = 1.f / __shfl(l, 4 * g + 2);
    float i3 = 1.f / __shfl(l, 4 * g + 3);
    int rowb = b * LQ + q0 + w * 16 + 4 * g;
#pragma unroll
    for (int n = 0; n < 16; ++n) {
        int col = n * 16 + qn;
        ctx_g[(size_t)(rowb + 0) * F + col] = f2bf(ctx[n][0] * i0);
        ctx_g[(size_t)(rowb + 1) * F + col] = f2bf(ctx[n][1] * i1);
        ctx_g[(size_t)(rowb + 2) * F + col] = f2bf(ctx[n][2] * i2);
        ctx_g[(size_t)(rowb + 3) * F + col] = f2bf(ctx[n][3] * i3);
    }
}

// ---------------------------------------------------------------------------
// out[i][e] = sum_f ctxb[i][f] * Nt[e][f] + cvec[e]   (plain bf16 NT GEMM)
__global__ __launch_bounds__(256) void gemm2_kernel(
    const u16* __restrict__ Ab, const u16* __restrict__ Bb,
    const float* __restrict__ cvec, float* __restrict__ out)
{
    __shared__ u16 Asb[64][40];
    __shared__ u16 Bsb[256][40];
    const int tid = threadIdx.x;
    const int w = tid >> 6, lane = tid & 63;
    const int g = lane >> 4, qn = lane & 15;
    const int wr = w >> 1, wc = w & 1;
    const int m0 = blockIdx.x * 64, e0 = blockIdx.y * 256;

    f4v acc[2][8];
#pragma unroll
    for (int i = 0; i < 2; ++i)
#pragma unroll
        for (int j = 0; j < 8; ++j) acc[i][j] = (f4v){0.f, 0.f, 0.f, 0.f};

    for (int k0 = 0; k0 < F; k0 += 32) {
        __syncthreads();
        {
            int r = tid & 63, c = (tid >> 6) * 8;
            *(s8v*)&Asb[r][c] = *(const s8v*)(Ab + (size_t)(m0 + r) * F + k0 + c);
            const u16* s = Bb + (size_t)(e0 + tid) * F + k0;
#pragma unroll
            for (int i = 0; i < 4; ++i)
                *(s8v*)&Bsb[tid][i * 8] = *(const s8v*)(s + i * 8);
        }
        __syncthreads();

        s8v ah[2], bh[8];
#pragma unroll
        for (int mt = 0; mt < 2; ++mt)
            ah[mt] = *(const s8v*)&Asb[wr * 32 + mt * 16 + qn][g * 8];
#pragma unroll
        for (int nt = 0; nt < 8; ++nt)
            bh[nt] = *(const s8v*)&Bsb[wc * 128 + nt * 16 + qn][g * 8];
#pragma unroll
        for (int mt = 0; mt < 2; ++mt)
#pragma unroll
            for (int nt = 0; nt < 8; ++nt)
                acc[mt][nt] = MF(ah[mt], bh[nt], acc[mt][nt]);
    }

#pragma unroll
    for (int mt = 0; mt < 2; ++mt)
#pragma unroll
        for (int nt = 0; nt < 8; ++nt)
#pragma unroll
            for (int r = 0; r < 4; ++r) {
                int gm = m0 + wr * 32 + mt * 16 + 4 * g + r;
                int gn = e0 + wc * 128 + nt * 16 + qn;
                out[(size_t)gm * E + gn] = acc[mt][nt][r] + cvec[gn];
            }
}

// ---------------------------------------------------------------------------
extern "C" void kernel_launch(void* const* d_in, const int* in_sizes, int n_in,
                              void* d_out, int out_size, void* d_ws, size_t ws_size,
                              hipStream_t stream)
{
    const float* x  = (const float*)d_in[0];   // [B,LQ,E]
    const float* y  = (const float*)d_in[1];   // [B,LK,F]
    const float* Wq = (const float*)d_in[2];
    const float* bq = (const float*)d_in[3];
    const float* Wk = (const float*)d_in[4];
    // d_in[5] = bk: contributes a per-row constant to scores -> softmax-invariant, unused.
    const float* Wv = (const float*)d_in[6];
    const float* bv = (const float*)d_in[7];
    const float* Wo = (const float*)d_in[8];
    const float* bo = (const float*)d_in[9];
    float* out = (float*)d_out;

    char* ws = (char*)d_ws;
    size_t off = 0;
    auto alloc = [&](size_t bytes) -> char* {
        char* p = ws + off;
        off = (off + bytes + 255) & ~(size_t)255;
        return p;
    };
    float* Mt   = (float*)alloc(sizeof(float) * F * E);        // M^T [F][E]
    float* wvec = (float*)alloc(sizeof(float) * F);
    float* cvec = (float*)alloc(sizeof(float) * E);
    u16* Nt   = (u16*)alloc(sizeof(u16) * E * F);              // N^T [E][F] bf16
    u16* qh   = (u16*)alloc(sizeof(u16) * (size_t)BB * LQ * F);
    u16* ql   = (u16*)alloc(sizeof(u16) * (size_t)BB * LQ * F);
    u16* yh   = (u16*)alloc(sizeof(u16) * (size_t)BB * LK * F);
    u16* yl   = (u16*)alloc(sizeof(u16) * (size_t)BB * LK * F);
    u16* yT   = (u16*)alloc(sizeof(u16) * (size_t)BB * F * LK);
    u16* ctxb = (u16*)alloc(sizeof(u16) * (size_t)BB * LQ * F);
    (void)ws_size; (void)in_sizes; (void)n_in; (void)out_size;

    kvec_kernel<<<dim3(1), dim3(512), 0, stream>>>(Wk, bq, bv, Wo, bo, wvec, cvec);
    // Mt[f][e] = sum_a Wk[f][a] * Wq[e][a]
    splitnt<0><<<dim3(F / 64, E / 256), dim3(256), 0, stream>>>(
        Wk, Wq, Mt, nullptr, nullptr, nullptr);
    // Nt[e][f] = sum_a Wo[a][e] * Wv[f][a]
    splitnt<2><<<dim3(E / 64, F / 256), dim3(256), 0, stream>>>(
        Wo, Wv, nullptr, nullptr, Nt, nullptr);
    prep_kernel<<<dim3(LK / 64, BB), dim3(256), 0, stream>>>(y, yh, yl, yT);
    // q'[i][f] = sum_e x[i][e] * Mt[f][e] + wvec[f]  -> split bf16
    splitnt<1><<<dim3(BB * LQ / 64, F / 256), dim3(256), 0, stream>>>(
        x, Mt, nullptr, wvec, qh, ql);
    flash_kernel<<<dim3(LQ / 64, BB), dim3(256), 0, stream>>>(
        qh, ql, yh, yl, yT, ctxb);
    gemm2_kernel<<<dim3(BB * LQ / 64, E / 256), dim3(256), 0, stream>>>(
        ctxb, Nt, cvec, out);
}